// Round 4
// baseline (4192.067 us; speedup 1.0000x reference)
//
#include <hip/hip_runtime.h>

typedef unsigned short u16;
typedef __attribute__((ext_vector_type(8))) short short8;
typedef __attribute__((ext_vector_type(4))) float f32x4;

#define NB 64
#define TLC 256
#define TLA 32
#define NE 300
#define NEP 320
#define NH 512
#define NG 2048
#define NH2 1024

#define MFMA16(a,b,c) __builtin_amdgcn_mfma_f32_16x16x32_bf16(a,b,c,0,0,0)

__device__ __forceinline__ float bf2f(u16 u){ unsigned int i=((unsigned int)u)<<16; float f; __builtin_memcpy(&f,&i,4); return f; }
__device__ __forceinline__ u16 f2bf(float f){ unsigned int i; __builtin_memcpy(&i,&f,4); i += 0x7fffu + ((i>>16)&1u); return (u16)(i>>16); }
__device__ __forceinline__ void split2(float v, u16& h, u16& l){ h=f2bf(v); l=f2bf(v - bf2f(h)); }

// ---------------- static device workspace ----------------
__device__ int   d_len[3*NB];
__device__ u16   d_Xch[(size_t)NB*TLC*NEP], d_Xcl[(size_t)NB*TLC*NEP];
__device__ u16   d_Xah[(size_t)NB*TLA*NEP], d_Xal[(size_t)NB*TLA*NEP];
__device__ u16   d_Wh[(size_t)4*NG*NEP],   d_Wl[(size_t)4*NG*NEP];
__device__ float d_bsum[4*NG];
__device__ float d_Gc[(size_t)2*NB*TLC*NG];
__device__ float d_Ga[(size_t)2*NB*TLA*NG];
__device__ float d_ctx_out[(size_t)NB*TLC*NH2];
__device__ float d_asp_out[(size_t)NB*TLA*NH2];
__device__ u16   d_hh[2][2][2*NB*NH];     // [grp][parity][(dir*NB+b)*NH+u]
__device__ u16   d_hl[2][2][2*NB*NH];
__device__ u16   d_cw3h[(size_t)NB*TLC*NH2], d_cw3l[(size_t)NB*TLC*NH2];
__device__ u16   d_abfh[(size_t)NB*TLA*NH2], d_abfl[(size_t)NB*TLA*NH2];
__device__ float d_ctx_pool[NB*NH2], d_asp_pool[NB*NH2];
__device__ float d_tvec[2][NB*NH2];
__device__ float d_av1[NB*TLC], d_av2[NB*TLA];
__device__ float d_algn[(size_t)NB*TLC*TLA];
__device__ float d_feat[4][NB*NH2];
// barrier state: each counter on its own 128B line (no false sharing between groups)
__device__ __align__(128) int d_barc0[32];
__device__ __align__(128) int d_barc1[32];
__device__ __align__(128) int d_barg0[32];
__device__ __align__(128) int d_barg1[32];

// ---------------- grid barrier, per-group (64 blocks each) ----------------
__device__ __forceinline__ void grid_bar(int grp){
  int* barc = grp ? d_barc1 : d_barc0;
  int* barg = grp ? d_barg1 : d_barg0;
  __syncthreads();
  if(threadIdx.x==0){
    __threadfence();
    int gen = __hip_atomic_load(barg, __ATOMIC_RELAXED, __HIP_MEMORY_SCOPE_AGENT);
    int a = __hip_atomic_fetch_add(barc, 1, __ATOMIC_ACQ_REL, __HIP_MEMORY_SCOPE_AGENT);
    if(a == 63){
      __hip_atomic_store(barc, 0, __ATOMIC_RELAXED, __HIP_MEMORY_SCOPE_AGENT);
      __hip_atomic_fetch_add(barg, 1, __ATOMIC_ACQ_REL, __HIP_MEMORY_SCOPE_AGENT);
    } else {
      while(__hip_atomic_load(barg, __ATOMIC_RELAXED, __HIP_MEMORY_SCOPE_AGENT) == gen)
        __builtin_amdgcn_s_sleep(2);
    }
    __threadfence();
  }
  __syncthreads();
}

// ---------------- lengths ----------------
__global__ void k_len(const int* __restrict__ traw, const int* __restrict__ aidx, const int* __restrict__ tleft){
  int b = blockIdx.x; int l = threadIdx.x;
  int c1=0,c2=0,c3=0;
  for(int t=l;t<TLC;t+=64) c1 += (traw[b*TLC+t]!=0);
  for(int t=l;t<TLA;t+=64) c2 += (aidx[b*TLA+t]!=0);
  for(int t=l;t<TLC;t+=64) c3 += (tleft[b*TLC+t]!=0);
  for(int o=32;o;o>>=1){ c1+=__shfl_down(c1,o); c2+=__shfl_down(c2,o); c3+=__shfl_down(c3,o); }
  if(l==0){ d_len[b]=c1; d_len[NB+b]=c2; d_len[2*NB+b]=c3; }
}

// ---------------- gather + split embeddings ----------------
__global__ void k_prep_x(const int* __restrict__ traw, const int* __restrict__ aidx, const float* __restrict__ emb){
  int m = blockIdx.x; int e = threadIdx.x;     // 320 threads
  if(m < NB*TLC){
    int tok = traw[m]; float v = (e<NE)? emb[(size_t)tok*NE+e] : 0.f;
    u16 h,l; split2(v,h,l);
    d_Xch[(size_t)m*NEP+e]=h; d_Xcl[(size_t)m*NEP+e]=l;
  } else {
    int mm = m - NB*TLC; int tok = aidx[mm]; float v = (e<NE)? emb[(size_t)tok*NE+e] : 0.f;
    u16 h,l; split2(v,h,l);
    d_Xah[(size_t)mm*NEP+e]=h; d_Xal[(size_t)mm*NEP+e]=l;
  }
}

// ---------------- split wih, sum biases ----------------
__global__ void k_prep_w(const float* w0,const float* w1,const float* w2,const float* w3,
                         const float* bi0,const float* bh0,const float* bi1,const float* bh1,
                         const float* bi2,const float* bh2,const float* bi3,const float* bh3){
  int r = blockIdx.x >> 11; int j = blockIdx.x & 2047; int e = threadIdx.x;
  const float* w = (r==0)?w0:(r==1)?w1:(r==2)?w2:w3;
  float v = (e<NE)? w[(size_t)j*NE+e] : 0.f;
  u16 h,l; split2(v,h,l);
  d_Wh[((size_t)r*NG+j)*NEP+e]=h; d_Wl[((size_t)r*NG+j)*NEP+e]=l;
  if(e==0){
    const float* bi = (r==0)?bi0:(r==1)?bi1:(r==2)?bi2:bi3;
    const float* bh = (r==0)?bh0:(r==1)?bh1:(r==2)?bh2:bh3;
    d_bsum[r*NG+j] = bi[j] + bh[j];
  }
}

// ---------------- zero outputs (padded positions must be exact 0) ----------------
__global__ void k_zero(){
  size_t n1 = (size_t)NB*TLC*NH2, n2 = (size_t)NB*TLA*NH2;
  size_t total = (n1+n2)/4;
  for(size_t i = (size_t)blockIdx.x*blockDim.x + threadIdx.x; i < total; i += (size_t)gridDim.x*blockDim.x){
    size_t e = i*4;
    float4 z = {0.f,0.f,0.f,0.f};
    if(e < n1) *(float4*)&d_ctx_out[e] = z;
    else       *(float4*)&d_asp_out[e-n1] = z;
  }
}

// ---------------- input-gate GEMM: G = X @ Wih^T + bsum (3-product hi/lo bf16 MFMA) ----------------
__global__ __launch_bounds__(256) void k_gin(){
  __shared__ u16 Ah[64][40], Al[64][40], Bh[64][40], Bl[64][40];
  int nt = blockIdx.x;                  // 0..31 -> N tile
  int my = blockIdx.y;                  // 0..575 -> run + M tile
  int r, mt; const u16 *Xh, *Xl; float* G;
  if(my<512){ r = my>>8; mt = my&255; Xh=d_Xch; Xl=d_Xcl; G = d_Gc + (size_t)r*NB*TLC*NG; }
  else { int z = my-512; r = 2 + (z>>5); mt = z&31; Xh=d_Xah; Xl=d_Xal; G = d_Ga + (size_t)(r-2)*NB*TLA*NG; }
  int m0 = mt*64;
  if(r<2){ int b = m0>>8, t0 = m0&255; if(t0 >= d_len[b]) return; }
  const u16* Wrh = d_Wh + (size_t)r*NG*NEP;
  const u16* Wrl = d_Wl + (size_t)r*NG*NEP;
  int n0 = nt*64, tid = threadIdx.x;
  int wv = tid>>6, lane = tid&63;
  int mq = wv&1, nq = wv>>1;
  f32x4 acc[2][2] = {};
  int lrow = tid>>2, lpart = tid&3;
  int r16 = lane&15, koff = (lane>>4)*8;
  for(int k0=0;k0<NEP;k0+=32){
    __syncthreads();
    *(short8*)&Ah[lrow][lpart*8] = *(const short8*)&Xh[(size_t)(m0+lrow)*NEP + k0 + lpart*8];
    *(short8*)&Al[lrow][lpart*8] = *(const short8*)&Xl[(size_t)(m0+lrow)*NEP + k0 + lpart*8];
    *(short8*)&Bh[lrow][lpart*8] = *(const short8*)&Wrh[(size_t)(n0+lrow)*NEP + k0 + lpart*8];
    *(short8*)&Bl[lrow][lpart*8] = *(const short8*)&Wrl[(size_t)(n0+lrow)*NEP + k0 + lpart*8];
    __syncthreads();
    short8 fah0 = *(const short8*)&Ah[mq*32 + r16][koff];
    short8 fah1 = *(const short8*)&Ah[mq*32 + 16 + r16][koff];
    short8 fal0 = *(const short8*)&Al[mq*32 + r16][koff];
    short8 fal1 = *(const short8*)&Al[mq*32 + 16 + r16][koff];
    short8 fbh0 = *(const short8*)&Bh[nq*32 + r16][koff];
    short8 fbh1 = *(const short8*)&Bh[nq*32 + 16 + r16][koff];
    short8 fbl0 = *(const short8*)&Bl[nq*32 + r16][koff];
    short8 fbl1 = *(const short8*)&Bl[nq*32 + 16 + r16][koff];
    acc[0][0]=MFMA16(fah0,fbh0,acc[0][0]); acc[0][0]=MFMA16(fal0,fbh0,acc[0][0]); acc[0][0]=MFMA16(fah0,fbl0,acc[0][0]);
    acc[0][1]=MFMA16(fah0,fbh1,acc[0][1]); acc[0][1]=MFMA16(fal0,fbh1,acc[0][1]); acc[0][1]=MFMA16(fah0,fbl1,acc[0][1]);
    acc[1][0]=MFMA16(fah1,fbh0,acc[1][0]); acc[1][0]=MFMA16(fal1,fbh0,acc[1][0]); acc[1][0]=MFMA16(fah1,fbl0,acc[1][0]);
    acc[1][1]=MFMA16(fah1,fbh1,acc[1][1]); acc[1][1]=MFMA16(fal1,fbh1,acc[1][1]); acc[1][1]=MFMA16(fah1,fbl1,acc[1][1]);
  }
  int r4 = lane>>4;
  #pragma unroll
  for(int mi=0;mi<2;mi++)
  #pragma unroll
  for(int ni=0;ni<2;ni++){
    int j = n0 + nq*32 + ni*16 + r16;
    float bs = d_bsum[r*NG + j];
    #pragma unroll
    for(int q=0;q<4;q++){
      int m = m0 + mq*32 + mi*16 + r4*4 + q;
      G[(size_t)m*NG + j] = acc[mi][ni][q] + bs;
    }
  }
}

// ---------------- persistent bidirectional LSTMs (both ctx & asp in one launch) ----------------
// grid 128: grp = bid>>6 (0=ctx,1=asp); within group: dir = (bid&63)>>5, 16-unit slice.
// h double-buffered by step parity (read t&1, write (t+1)&1) -> single barrier per step, no WAR race.
__global__ __launch_bounds__(256) void k_lstm_all(const float* __restrict__ whh_cf, const float* __restrict__ whh_cb,
                                                  const float* __restrict__ whh_af, const float* __restrict__ whh_ab){
  __shared__ u16 whs[4*16*512];                      // 64KB, XOR-swizzled
  int bid = blockIdx.x, tid = threadIdx.x;
  int grp = bid>>6, b6 = bid&63;
  int dir = b6>>5, u0 = (b6&31)*16;
  int T = grp ? TLA : TLC;
  const float* Gbase = grp ? d_Ga : d_Gc;
  float* outb = grp ? d_asp_out : d_ctx_out;
  const int* lens = d_len + grp*NB;
  const float* whh = grp ? (dir?whh_ab:whh_af) : (dir?whh_cb:whh_cf);

  { // stage whh slice as bf16-hi, swizzled: rows {g*512+u0+rr}
    int row = tid>>2, seg = tid&3;
    int g = row>>4, rr = row&15;
    const float* src = whh + (size_t)(g*NH + u0 + rr)*NH + seg*128;
    int base = (g*16+rr)<<9;
    int swz = (rr&7)<<3;
    for(int s=0;s<128;s+=8){
      u16 tmp[8];
      #pragma unroll
      for(int q=0;q<8;q++) tmp[q] = f2bf(src[s+q]);
      *(short8*)&whs[base + ((seg*128+s) ^ swz)] = *(const short8*)tmp;
    }
  }
  // zero both parities of this block's h columns
  for(int x=tid; x<NB*16; x+=256){
    int b = x>>4, uu = u0 + (x&15); int ix = (dir*NB+b)*NH+uu;
    d_hh[grp][0][ix]=0; d_hh[grp][1][ix]=0; d_hl[grp][0][ix]=0; d_hl[grp][1][ix]=0;
  }

  int wv = tid>>6, lane = tid&63;
  int r16 = lane&15, bq = lane>>4;
  int u = u0 + r16;
  int bA = wv*16 + r16;
  int koff = bq*8;
  int swz = (r16&7)<<3;
  int wb0 = (0+r16)<<9, wb1 = (16+r16)<<9, wb2 = (32+r16)<<9, wb3 = (48+r16)<<9;

  int len4[4]; float c4[4]={0,0,0,0}, h4[4]={0,0,0,0};
  int wmax = 0;
  #pragma unroll
  for(int q=0;q<4;q++){ len4[q] = lens[wv*16 + bq*4 + q]; wmax = max(wmax, len4[q]); }
  wmax = max(wmax, __shfl_xor(wmax, 16));
  wmax = max(wmax, __shfl_xor(wmax, 32));

  size_t hoffA = (size_t)(dir*NB + bA)*NH;
  const float* Gd = Gbase + (size_t)dir*NB*T*NG;

  grid_bar(grp);                                     // zeros + staging visible

  for(int t=0;t<T;t++){
    int par = t&1;
    if(t < wmax){
      const u16* hh = d_hh[grp][par] + hoffA;
      const u16* hl = d_hl[grp][par] + hoffA;
      u16* nhh = d_hh[grp][par^1];
      u16* nhl = d_hl[grp][par^1];
      f32x4 a0=0, a1=0, a2=0, a3=0;
      #pragma unroll
      for(int kc=0;kc<16;kc++){
        int kk = kc*32 + koff;
        short8 ah = *(const short8*)(hh + kk);
        short8 al = *(const short8*)(hl + kk);
        short8 w0 = *(const short8*)&whs[wb0 + (kk ^ swz)];
        short8 w1 = *(const short8*)&whs[wb1 + (kk ^ swz)];
        short8 w2 = *(const short8*)&whs[wb2 + (kk ^ swz)];
        short8 w3 = *(const short8*)&whs[wb3 + (kk ^ swz)];
        a0 = MFMA16(ah, w0, a0); a0 = MFMA16(al, w0, a0);
        a1 = MFMA16(ah, w1, a1); a1 = MFMA16(al, w1, a1);
        a2 = MFMA16(ah, w2, a2); a2 = MFMA16(al, w2, a2);
        a3 = MFMA16(ah, w3, a3); a3 = MFMA16(al, w3, a3);
      }
      #pragma unroll
      for(int q=0;q<4;q++){
        int b = wv*16 + bq*4 + q;
        if(t < len4[q]){
          int pos = (dir==0) ? t : (len4[q]-1-t);
          const float* gp = Gd + ((size_t)b*T + pos)*NG + u;
          float vi = a0[q] + gp[0];
          float vf = a1[q] + gp[NH];
          float vg = a2[q] + gp[2*NH];
          float vo = a3[q] + gp[3*NH];
          float ig = 1.f/(1.f+__expf(-vi));
          float fg = 1.f/(1.f+__expf(-vf));
          float gg = tanhf(vg);
          float og = 1.f/(1.f+__expf(-vo));
          c4[q] = fg*c4[q] + ig*gg;
          h4[q] = og*tanhf(c4[q]);
          outb[((size_t)b*T+pos)*NH2 + dir*NH + u] = h4[q];
        }
        // always refresh next-parity h (keeps frozen batches current)
        size_t ix = (size_t)(dir*NB+b)*NH + u;
        u16 hi, lo; split2(h4[q], hi, lo);
        nhh[ix] = hi; nhl[ix] = lo;
      }
    }
    grid_bar(grp);
  }
}

// ---------------- location weight + ctx pool + bf16 hi/lo side copies ----------------
__global__ void k_locpool(const float* __restrict__ w_u){
  int b = blockIdx.x; int d = blockIdx.y*128 + threadIdx.x;
  int alen = d_len[NB+b], sl = d_len[2*NB+b];
  int e_i = sl + alen - 1;
  float s = (float)sl, e = (float)e_i, sent = (float)TLC - (float)alen;
  float w3 = w_u[2*NH2 + d];
  float acc = 0.f;
  for(int t=0;t<TLC;t++){
    float w = (t < sl) ? (1.f - (s-(float)t)/sent) : ((t <= e_i) ? 0.f : (1.f - ((float)t-e)/sent));
    size_t ix = ((size_t)b*TLC + t)*NH2 + d;
    float v = d_ctx_out[ix] * w;
    d_ctx_out[ix] = v;
    u16 h,l; split2(v*w3, h, l);
    d_cw3h[ix]=h; d_cw3l[ix]=l;
    acc += v;
  }
  d_ctx_pool[b*NH2+d] = acc / (float)d_len[b];
}

__global__ void k_asppool(){
  int b = blockIdx.x; int d = blockIdx.y*128 + threadIdx.x;
  float acc=0.f;
  for(int t=0;t<TLA;t++){
    size_t ix = ((size_t)b*TLA+t)*NH2 + d; float v = d_asp_out[ix];
    u16 h,l; split2(v,h,l); d_abfh[ix]=h; d_abfl[ix]=l;
    acc += v;
  }
  d_asp_pool[b*NH2+d] = acc/(float)d_len[NB+b];
}

// ---------------- t = W(2H,2H) @ pool (associativity trick) ----------------
__global__ void k_tvec(const float* __restrict__ W, int sel){
  __shared__ float ps[NH2];
  int b = blockIdx.x; int k = blockIdx.y*64 + threadIdx.x;
  const float* pool = sel ? d_ctx_pool : d_asp_pool;
  float* out = sel ? d_tvec[1] : d_tvec[0];
  for(int i=threadIdx.x;i<NH2;i+=64) ps[i] = pool[b*NH2+i];
  __syncthreads();
  const float* wr = W + (size_t)k*NH2;
  float acc=0.f;
  for(int d=0;d<NH2;d+=4){
    float4 v = *(const float4*)(wr+d);
    acc += v.x*ps[d] + v.y*ps[d+1] + v.z*ps[d+2] + v.w*ps[d+3];
  }
  out[b*NH2+k] = acc;
}

// ---------------- av1 = ctx_out @ w1, av2 = asp_out @ w2 ----------------
__global__ void k_av(const float* __restrict__ w_u){
  int b = blockIdx.x; int wv = threadIdx.x>>6; int lane = threadIdx.x&63;
  int row = blockIdx.y*4 + wv;
  const float* src; const float* w; float* dst;
  if(row < TLC){ src = d_ctx_out + ((size_t)b*TLC+row)*NH2; w = w_u; dst = &d_av1[b*TLC+row]; }
  else { int j = row-TLC; src = d_asp_out + ((size_t)b*TLA+j)*NH2; w = w_u + NH2; dst = &d_av2[b*TLA+j]; }
  float acc=0.f;
  for(int d=lane*4; d<NH2; d+=256){
    float4 v = *(const float4*)(src+d);
    float4 ww = *(const float4*)(w+d);
    acc += v.x*ww.x + v.y*ww.y + v.z*ww.z + v.w*ww.w;
  }
  for(int o=32;o;o>>=1) acc += __shfl_down(acc,o);
  if(lane==0) *dst = acc;
}

// ---------------- align = av1 + av2 + (ctx*w3) @ asp^T (3-product hi/lo MFMA) ----------------
__global__ __launch_bounds__(256) void k_align(){
  int b = blockIdx.x; int tid = threadIdx.x; int wv = tid>>6, lane = tid&63;
  int i0 = wv*64; int r16 = lane&15; int koff = (lane>>4)*8;
  f32x4 acc[4][2] = {};
  const u16* Ahp = d_cw3h + (size_t)b*TLC*NH2;
  const u16* Alp = d_cw3l + (size_t)b*TLC*NH2;
  const u16* Bhp = d_abfh + (size_t)b*TLA*NH2;
  const u16* Blp = d_abfl + (size_t)b*TLA*NH2;
  for(int kc=0;kc<32;kc++){
    int k = kc*32 + koff;
    short8 fbh0 = *(const short8*)&Bhp[(size_t)r16*NH2 + k];
    short8 fbh1 = *(const short8*)&Bhp[(size_t)(16+r16)*NH2 + k];
    short8 fbl0 = *(const short8*)&Blp[(size_t)r16*NH2 + k];
    short8 fbl1 = *(const short8*)&Blp[(size_t)(16+r16)*NH2 + k];
    #pragma unroll
    for(int mi=0;mi<4;mi++){
      short8 fah = *(const short8*)&Ahp[(size_t)(i0+mi*16+r16)*NH2 + k];
      short8 fal = *(const short8*)&Alp[(size_t)(i0+mi*16+r16)*NH2 + k];
      acc[mi][0]=MFMA16(fah,fbh0,acc[mi][0]); acc[mi][0]=MFMA16(fal,fbh0,acc[mi][0]); acc[mi][0]=MFMA16(fah,fbl0,acc[mi][0]);
      acc[mi][1]=MFMA16(fah,fbh1,acc[mi][1]); acc[mi][1]=MFMA16(fal,fbh1,acc[mi][1]); acc[mi][1]=MFMA16(fah,fbl1,acc[mi][1]);
    }
  }
  int r4 = lane>>4;
  #pragma unroll
  for(int mi=0;mi<4;mi++)
  #pragma unroll
  for(int ni=0;ni<2;ni++){
    int jj = ni*16 + r16;
    float a2 = d_av2[b*TLA + jj];
    #pragma unroll
    for(int q=0;q<4;q++){
      int i = i0 + mi*16 + r4*4 + q;
      d_algn[((size_t)b*TLC + i)*TLA + jj] = acc[mi][ni][q] + d_av1[b*TLC+i] + a2;
    }
  }
}

// ---------------- attention features ----------------
__global__ __launch_bounds__(256) void k_attn(){
  __shared__ float sp[TLC];
  __shared__ float sq[TLA];
  __shared__ float st[NH2];
  __shared__ float red[256];
  int b = blockIdx.x; int tid = threadIdx.x;
  const float* cout = d_ctx_out + (size_t)b*TLC*NH2;
  const float* aout = d_asp_out + (size_t)b*TLA*NH2;

  { // P1: max over j, softmax over i
    const float* ar = d_algn + ((size_t)b*TLC + tid)*TLA;
    float m = ar[0];
    for(int j=1;j<TLA;j++) m = fmaxf(m, ar[j]);
    red[tid] = m; __syncthreads();
    for(int s=128;s;s>>=1){ if(tid<s) red[tid] = fmaxf(red[tid], red[tid+s]); __syncthreads(); }
    float M = red[0]; __syncthreads();
    float e_ = __expf(m - M);
    red[tid] = e_; __syncthreads();
    for(int s=128;s;s>>=1){ if(tid<s) red[tid] += red[tid+s]; __syncthreads(); }
    float S = red[0]; __syncthreads();
    sp[tid] = e_/S; __syncthreads();
  }
  // P2: f_asp2ctx
  for(int d=tid; d<NH2; d+=256){
    float a=0.f;
    for(int i=0;i<TLC;i++) a += sp[i]*cout[(size_t)i*NH2 + d];
    d_feat[1][b*NH2+d] = a;
  }
  __syncthreads();
  { // P3: c_asp2ctx via t_a2c
    for(int i2=tid;i2<NH2;i2+=256) st[i2] = d_tvec[0][b*NH2+i2];
    __syncthreads();
    const float* crow = cout + (size_t)tid*NH2;
    float lg = 0.f;
    for(int d=0;d<NH2;d+=4){ float4 v = *(const float4*)(crow+d); lg += v.x*st[d]+v.y*st[d+1]+v.z*st[d+2]+v.w*st[d+3]; }
    red[tid] = lg; __syncthreads();
    for(int s=128;s;s>>=1){ if(tid<s) red[tid] = fmaxf(red[tid], red[tid+s]); __syncthreads(); }
    float M = red[0]; __syncthreads();
    float e_ = __expf(lg - M);
    red[tid] = e_; __syncthreads();
    for(int s=128;s;s>>=1){ if(tid<s) red[tid] += red[tid+s]; __syncthreads(); }
    float S = red[0]; __syncthreads();
    sp[tid] = e_/S; __syncthreads();
    for(int d=tid; d<NH2; d+=256){
      float a=0.f;
      for(int i=0;i<TLC;i++) a += sp[i]*cout[(size_t)i*NH2 + d];
      d_feat[0][b*NH2+d] = a;
    }
    __syncthreads();
  }
  { // P4: max over i, softmax over j
    int jj = tid&31, grp = tid>>5;
    float pm = -1e30f;
    for(int i=grp;i<TLC;i+=8) pm = fmaxf(pm, d_algn[((size_t)b*TLC+i)*TLA + jj]);
    red[tid] = pm; __syncthreads();
    if(tid<32){
      float m2 = red[tid];
      for(int g=1;g<8;g++) m2 = fmaxf(m2, red[g*32+tid]);
      float Mx = m2;
      for(int o=16;o;o>>=1) Mx = fmaxf(Mx, __shfl_xor(Mx,o,32));
      float ee = __expf(m2 - Mx);
      float Ss = ee;
      for(int o=16;o;o>>=1) Ss += __shfl_xor(Ss,o,32);
      sq[tid] = ee/Ss;
    }
    __syncthreads();
  }
  // P5: f_ctx2asp
  for(int d=tid; d<NH2; d+=256){
    float a=0.f;
    for(int j=0;j<TLA;j++) a += sq[j]*aout[(size_t)j*NH2 + d];
    d_feat[2][b*NH2+d] = a;
  }
  __syncthreads();
  { // P6: c_ctx2asp logits via t_c2a
    for(int i2=tid;i2<NH2;i2+=256) st[i2] = d_tvec[1][b*NH2+i2];
    __syncthreads();
    int j6 = tid>>3, seg = tid&7;
    const float* arow = aout + (size_t)j6*NH2;
    float p6 = 0.f;
    for(int d=seg*128; d<seg*128+128; d+=4){ float4 v = *(const float4*)(arow+d); p6 += v.x*st[d]+v.y*st[d+1]+v.z*st[d+2]+v.w*st[d+3]; }
    red[tid] = p6; __syncthreads();
    if(tid<32){
      float lj = 0.f;
      for(int s=0;s<8;s++) lj += red[tid*8+s];
      float Mx = lj;
      for(int o=16;o;o>>=1) Mx = fmaxf(Mx, __shfl_xor(Mx,o,32));
      float ee = __expf(lj - Mx);
      float Ss = ee;
      for(int o=16;o;o>>=1) Ss += __shfl_xor(Ss,o,32);
      sq[tid] = ee/Ss;
    }
    __syncthreads();
  }
  // P7: c_ctx2asp
  for(int d=tid; d<NH2; d+=256){
    float a=0.f;
    for(int j=0;j<TLA;j++) a += sq[j]*aout[(size_t)j*NH2 + d];
    d_feat[3][b*NH2+d] = a;
  }
}

// ---------------- final dense ----------------
__global__ void k_final(const float* __restrict__ dw, const float* __restrict__ db, float* __restrict__ out){
  int b = blockIdx.x; int wv = threadIdx.x>>6; int lane = threadIdx.x&63;
  const float* fs[4] = {d_feat[0]+b*NH2, d_feat[1]+b*NH2, d_feat[2]+b*NH2, d_feat[3]+b*NH2};
  float acc=0.f;
  for(int e=lane*4; e<4096; e+=256){
    const float* f = fs[e>>10]; int d = e&1023;
    const float* w = dw + (size_t)wv*4096 + e;
    acc += f[d]*w[0] + f[d+1]*w[1] + f[d+2]*w[2] + f[d+3]*w[3];
  }
  for(int o=32;o;o>>=1) acc += __shfl_down(acc,o);
  if(lane==0) out[b*3+wv] = acc + db[wv];
}

// ---------------- host ----------------
extern "C" void kernel_launch(void* const* d_in, const int* in_sizes, int n_in,
                              void* d_out, int out_size, void* d_ws, size_t ws_size,
                              hipStream_t stream){
  const int*   traw  = (const int*)d_in[0];
  const int*   aidx  = (const int*)d_in[1];
  const int*   tleft = (const int*)d_in[2];
  const float* emb   = (const float*)d_in[3];
  const float* w_a2c = (const float*)d_in[4];
  const float* w_c2a = (const float*)d_in[5];
  const float* w_u   = (const float*)d_in[6];
  const float* dw    = (const float*)d_in[7];
  const float* db    = (const float*)d_in[8];
  // LSTM params: runs r=0..3 at d_in[9+4r..12+4r] = wih, whh, bih, bhh
  k_len<<<dim3(NB), dim3(64), 0, stream>>>(traw, aidx, tleft);
  k_prep_x<<<dim3(NB*TLC + NB*TLA), dim3(NEP), 0, stream>>>(traw, aidx, emb);
  k_prep_w<<<dim3(4*NG), dim3(NEP), 0, stream>>>(
      (const float*)d_in[9], (const float*)d_in[13], (const float*)d_in[17], (const float*)d_in[21],
      (const float*)d_in[11], (const float*)d_in[12], (const float*)d_in[15], (const float*)d_in[16],
      (const float*)d_in[19], (const float*)d_in[20], (const float*)d_in[23], (const float*)d_in[24]);
  k_zero<<<dim3(2048), dim3(256), 0, stream>>>();
  k_gin<<<dim3(32, 576), dim3(256), 0, stream>>>();
  k_lstm_all<<<dim3(128), dim3(256), 0, stream>>>(
      (const float*)d_in[10], (const float*)d_in[14], (const float*)d_in[18], (const float*)d_in[22]);
  k_locpool<<<dim3(NB, 8), dim3(128), 0, stream>>>(w_u);
  k_asppool<<<dim3(NB, 8), dim3(128), 0, stream>>>();
  k_tvec<<<dim3(NB, 16), dim3(64), 0, stream>>>(w_a2c, 0);
  k_tvec<<<dim3(NB, 16), dim3(64), 0, stream>>>(w_c2a, 1);
  k_av<<<dim3(NB, 72), dim3(256), 0, stream>>>(w_u);
  k_align<<<dim3(NB), dim3(256), 0, stream>>>();
  k_attn<<<dim3(NB), dim3(256), 0, stream>>>();
  k_final<<<dim3(NB), dim3(192), 0, stream>>>(dw, db, (float*)d_out);
}

// Round 5
// 4070.978 us; speedup vs baseline: 1.0297x; 1.0297x over previous
//
#include <hip/hip_runtime.h>

typedef unsigned short u16;
typedef __attribute__((ext_vector_type(8))) short short8;
typedef __attribute__((ext_vector_type(4))) float f32x4;

#define NB 64
#define TLC 256
#define TLA 32
#define NE 300
#define NEP 320
#define NH 512
#define NG 2048
#define NH2 1024
#define SCOPE_AGT __HIP_MEMORY_SCOPE_AGENT

#define MFMA16(a,b,c) __builtin_amdgcn_mfma_f32_16x16x32_bf16(a,b,c,0,0,0)

__device__ __forceinline__ float bf2f(u16 u){ unsigned int i=((unsigned int)u)<<16; float f; __builtin_memcpy(&f,&i,4); return f; }
__device__ __forceinline__ u16 f2bf(float f){ unsigned int i; __builtin_memcpy(&i,&f,4); i += 0x7fffu + ((i>>16)&1u); return (u16)(i>>16); }
__device__ __forceinline__ void split2(float v, u16& h, u16& l){ h=f2bf(v); l=f2bf(v - bf2f(h)); }

union U8 { unsigned int d[4]; short8 s; };

// ---------------- static device workspace ----------------
__device__ int   d_len[3*NB];
__device__ u16   d_Xch[(size_t)NB*TLC*NEP], d_Xcl[(size_t)NB*TLC*NEP];
__device__ u16   d_Xah[(size_t)NB*TLA*NEP], d_Xal[(size_t)NB*TLA*NEP];
__device__ u16   d_Wh[(size_t)4*NG*NEP],   d_Wl[(size_t)4*NG*NEP];
__device__ float d_bsum[4*NG];
__device__ float d_Gc[(size_t)2*NB*TLC*NG];
__device__ float d_Ga[(size_t)2*NB*TLA*NG];
__device__ float d_ctx_out[(size_t)NB*TLC*NH2];
__device__ float d_asp_out[(size_t)NB*TLA*NH2];
__device__ unsigned int d_hx[2][2][(size_t)2*NB*NH];   // [grp][par][(dir*NB+b)*NH+u] packed (hi<<16|lo)
__device__ u16   d_cw3h[(size_t)NB*TLC*NH2], d_cw3l[(size_t)NB*TLC*NH2];
__device__ u16   d_abfh[(size_t)NB*TLA*NH2], d_abfl[(size_t)NB*TLA*NH2];
__device__ float d_ctx_pool[NB*NH2], d_asp_pool[NB*NH2];
__device__ float d_tvec[2][NB*NH2];
__device__ float d_av1[NB*TLC], d_av2[NB*TLA];
__device__ float d_algn[(size_t)NB*TLC*TLA];
__device__ float d_feat[4][NB*NH2];
// barrier flags: [domain][slice] arrival (128B stride), [domain] generation
__device__ __align__(128) int d_arr[4][32][32];
__device__ __align__(128) int d_gen[4][32];

// ---------------- fence-free grid barrier: drain + flag-array + aggregator ----------------
__device__ __forceinline__ void lbar(int dom, int b5, bool agg, int ep){
  asm volatile("s_waitcnt vmcnt(0)" ::: "memory");   // every thread drains its own sc1 stores
  __syncthreads();                                   // whole block's stores are at L3
  int tid = threadIdx.x;
  if(tid==0)
    __hip_atomic_store(&d_arr[dom][b5][0], ep, __ATOMIC_RELAXED, SCOPE_AGT);
  if(agg){
    if(tid<32){
      while(__hip_atomic_load(&d_arr[dom][tid][0], __ATOMIC_RELAXED, SCOPE_AGT) < ep)
        __builtin_amdgcn_s_sleep(1);
    }
    if(tid==0)
      __hip_atomic_store(&d_gen[dom][0], ep, __ATOMIC_RELAXED, SCOPE_AGT);
  }
  if(tid==0){
    while(__hip_atomic_load(&d_gen[dom][0], __ATOMIC_RELAXED, SCOPE_AGT) < ep)
      __builtin_amdgcn_s_sleep(1);
  }
  __syncthreads();
}

// ---------------- lengths ----------------
__global__ void k_len(const int* __restrict__ traw, const int* __restrict__ aidx, const int* __restrict__ tleft){
  int b = blockIdx.x; int l = threadIdx.x;
  int c1=0,c2=0,c3=0;
  for(int t=l;t<TLC;t+=64) c1 += (traw[b*TLC+t]!=0);
  for(int t=l;t<TLA;t+=64) c2 += (aidx[b*TLA+t]!=0);
  for(int t=l;t<TLC;t+=64) c3 += (tleft[b*TLC+t]!=0);
  for(int o=32;o;o>>=1){ c1+=__shfl_down(c1,o); c2+=__shfl_down(c2,o); c3+=__shfl_down(c3,o); }
  if(l==0){ d_len[b]=c1; d_len[NB+b]=c2; d_len[2*NB+b]=c3; }
}

// ---------------- gather + split embeddings ----------------
__global__ void k_prep_x(const int* __restrict__ traw, const int* __restrict__ aidx, const float* __restrict__ emb){
  int m = blockIdx.x; int e = threadIdx.x;     // 320 threads
  if(m < NB*TLC){
    int tok = traw[m]; float v = (e<NE)? emb[(size_t)tok*NE+e] : 0.f;
    u16 h,l; split2(v,h,l);
    d_Xch[(size_t)m*NEP+e]=h; d_Xcl[(size_t)m*NEP+e]=l;
  } else {
    int mm = m - NB*TLC; int tok = aidx[mm]; float v = (e<NE)? emb[(size_t)tok*NE+e] : 0.f;
    u16 h,l; split2(v,h,l);
    d_Xah[(size_t)mm*NEP+e]=h; d_Xal[(size_t)mm*NEP+e]=l;
  }
}

// ---------------- split wih, sum biases ----------------
__global__ void k_prep_w(const float* w0,const float* w1,const float* w2,const float* w3,
                         const float* bi0,const float* bh0,const float* bi1,const float* bh1,
                         const float* bi2,const float* bh2,const float* bi3,const float* bh3){
  int r = blockIdx.x >> 11; int j = blockIdx.x & 2047; int e = threadIdx.x;
  const float* w = (r==0)?w0:(r==1)?w1:(r==2)?w2:w3;
  float v = (e<NE)? w[(size_t)j*NE+e] : 0.f;
  u16 h,l; split2(v,h,l);
  d_Wh[((size_t)r*NG+j)*NEP+e]=h; d_Wl[((size_t)r*NG+j)*NEP+e]=l;
  if(e==0){
    const float* bi = (r==0)?bi0:(r==1)?bi1:(r==2)?bi2:bi3;
    const float* bh = (r==0)?bh0:(r==1)?bh1:(r==2)?bh2:bh3;
    d_bsum[r*NG+j] = bi[j] + bh[j];
  }
}

// ---------------- zero outputs + reset barrier flags ----------------
__global__ void k_zero(){
  if(blockIdx.x==0 && threadIdx.x<128){
    int dm = threadIdx.x>>5, sl = threadIdx.x&31;
    __hip_atomic_store(&d_arr[dm][sl][0], 0, __ATOMIC_RELAXED, SCOPE_AGT);
    if(sl==0) __hip_atomic_store(&d_gen[dm][0], 0, __ATOMIC_RELAXED, SCOPE_AGT);
  }
  size_t n1 = (size_t)NB*TLC*NH2, n2 = (size_t)NB*TLA*NH2;
  size_t total = (n1+n2)/4;
  for(size_t i = (size_t)blockIdx.x*blockDim.x + threadIdx.x; i < total; i += (size_t)gridDim.x*blockDim.x){
    size_t e = i*4;
    float4 z = {0.f,0.f,0.f,0.f};
    if(e < n1) *(float4*)&d_ctx_out[e] = z;
    else       *(float4*)&d_asp_out[e-n1] = z;
  }
}

// ---------------- input-gate GEMM: G = X @ Wih^T + bsum (3-product hi/lo bf16 MFMA) ----------------
__global__ __launch_bounds__(256) void k_gin(){
  __shared__ u16 Ah[64][40], Al[64][40], Bh[64][40], Bl[64][40];
  int nt = blockIdx.x;                  // 0..31 -> N tile
  int my = blockIdx.y;                  // 0..575 -> run + M tile
  int r, mt; const u16 *Xh, *Xl; float* G;
  if(my<512){ r = my>>8; mt = my&255; Xh=d_Xch; Xl=d_Xcl; G = d_Gc + (size_t)r*NB*TLC*NG; }
  else { int z = my-512; r = 2 + (z>>5); mt = z&31; Xh=d_Xah; Xl=d_Xal; G = d_Ga + (size_t)(r-2)*NB*TLA*NG; }
  int m0 = mt*64;
  if(r<2){ int b = m0>>8, t0 = m0&255; if(t0 >= d_len[b]) return; }
  const u16* Wrh = d_Wh + (size_t)r*NG*NEP;
  const u16* Wrl = d_Wl + (size_t)r*NG*NEP;
  int n0 = nt*64, tid = threadIdx.x;
  int wv = tid>>6, lane = tid&63;
  int mq = wv&1, nq = wv>>1;
  f32x4 acc[2][2] = {};
  int lrow = tid>>2, lpart = tid&3;
  int r16 = lane&15, koff = (lane>>4)*8;
  for(int k0=0;k0<NEP;k0+=32){
    __syncthreads();
    *(short8*)&Ah[lrow][lpart*8] = *(const short8*)&Xh[(size_t)(m0+lrow)*NEP + k0 + lpart*8];
    *(short8*)&Al[lrow][lpart*8] = *(const short8*)&Xl[(size_t)(m0+lrow)*NEP + k0 + lpart*8];
    *(short8*)&Bh[lrow][lpart*8] = *(const short8*)&Wrh[(size_t)(n0+lrow)*NEP + k0 + lpart*8];
    *(short8*)&Bl[lrow][lpart*8] = *(const short8*)&Wrl[(size_t)(n0+lrow)*NEP + k0 + lpart*8];
    __syncthreads();
    short8 fah0 = *(const short8*)&Ah[mq*32 + r16][koff];
    short8 fah1 = *(const short8*)&Ah[mq*32 + 16 + r16][koff];
    short8 fal0 = *(const short8*)&Al[mq*32 + r16][koff];
    short8 fal1 = *(const short8*)&Al[mq*32 + 16 + r16][koff];
    short8 fbh0 = *(const short8*)&Bh[nq*32 + r16][koff];
    short8 fbh1 = *(const short8*)&Bh[nq*32 + 16 + r16][koff];
    short8 fbl0 = *(const short8*)&Bl[nq*32 + r16][koff];
    short8 fbl1 = *(const short8*)&Bl[nq*32 + 16 + r16][koff];
    acc[0][0]=MFMA16(fah0,fbh0,acc[0][0]); acc[0][0]=MFMA16(fal0,fbh0,acc[0][0]); acc[0][0]=MFMA16(fah0,fbl0,acc[0][0]);
    acc[0][1]=MFMA16(fah0,fbh1,acc[0][1]); acc[0][1]=MFMA16(fal0,fbh1,acc[0][1]); acc[0][1]=MFMA16(fah0,fbl1,acc[0][1]);
    acc[1][0]=MFMA16(fah1,fbh0,acc[1][0]); acc[1][0]=MFMA16(fal1,fbh0,acc[1][0]); acc[1][0]=MFMA16(fah1,fbl0,acc[1][0]);
    acc[1][1]=MFMA16(fah1,fbh1,acc[1][1]); acc[1][1]=MFMA16(fal1,fbh1,acc[1][1]); acc[1][1]=MFMA16(fah1,fbl1,acc[1][1]);
  }
  int r4 = lane>>4;
  #pragma unroll
  for(int mi=0;mi<2;mi++)
  #pragma unroll
  for(int ni=0;ni<2;ni++){
    int j = n0 + nq*32 + ni*16 + r16;
    float bs = d_bsum[r*NG + j];
    #pragma unroll
    for(int q=0;q<4;q++){
      int m = m0 + mq*32 + mi*16 + r4*4 + q;
      G[(size_t)m*NG + j] = acc[mi][ni][q] + bs;
    }
  }
}

// ---------------- persistent bidirectional LSTMs ----------------
// grid 128: grp=bid>>6 (0=ctx,1=asp); dir=(bid&63)>>5; 16-unit slice b5=bid&31.
// h exchanged via sc1 (device-coherent, L2-bypassing) loads/stores; fence-free flag barrier.
__global__ __launch_bounds__(256) void k_lstm_all(const float* __restrict__ whh_cf, const float* __restrict__ whh_cb,
                                                  const float* __restrict__ whh_af, const float* __restrict__ whh_ab){
  __shared__ u16 whs[4*16*512];                      // 64KB, XOR-swizzled
  int bid = blockIdx.x, tid = threadIdx.x;
  int grp = bid>>6, b6 = bid&63;
  int dir = b6>>5, b5 = b6&31, u0 = b5*16;
  int dom = grp*2 + dir;
  bool agg = (b5==0);
  int T = grp ? TLA : TLC;
  const float* Gbase = grp ? d_Ga : d_Gc;
  float* outb = grp ? d_asp_out : d_ctx_out;
  const int* lens = d_len + grp*NB;
  const float* whh = grp ? (dir?whh_ab:whh_af) : (dir?whh_cb:whh_cf);

  { // stage whh slice as bf16-hi, swizzled: rows {g*512+u0+rr}
    int row = tid>>2, seg = tid&3;
    int g = row>>4, rr = row&15;
    const float* src = whh + (size_t)(g*NH + u0 + rr)*NH + seg*128;
    int base = (g*16+rr)<<9;
    int swz2 = (rr&7)<<3;
    for(int s=0;s<128;s+=8){
      u16 tmp[8];
      #pragma unroll
      for(int q=0;q<8;q++) tmp[q] = f2bf(src[s+q]);
      *(short8*)&whs[base + ((seg*128+s) ^ swz2)] = *(const short8*)tmp;
    }
  }
  // zero both parities of this block's h columns (sc1 so no stale L2 copies can exist)
  for(int x=tid; x<NB*16; x+=256){
    int b = x>>4, uu = u0 + (x&15); size_t ix = (size_t)(dir*NB+b)*NH+uu;
    __hip_atomic_store(&d_hx[grp][0][ix], 0u, __ATOMIC_RELAXED, SCOPE_AGT);
    __hip_atomic_store(&d_hx[grp][1][ix], 0u, __ATOMIC_RELAXED, SCOPE_AGT);
  }

  int wv = tid>>6, lane = tid&63;
  int r16 = lane&15, bq = lane>>4;
  int u = u0 + r16;
  int bA = wv*16 + r16;                     // batch this lane LOADS h for
  int koff = bq*8;
  int swz = (r16&7)<<3;
  int wb0 = (0+r16)<<9, wb1 = (16+r16)<<9, wb2 = (32+r16)<<9, wb3 = (48+r16)<<9;

  int len4[4]; float c4[4]={0,0,0,0}, h4[4]={0,0,0,0};
  int wmax = 0;
  #pragma unroll
  for(int q=0;q<4;q++){ len4[q] = lens[wv*16 + bq*4 + q]; wmax = max(wmax, len4[q]); }
  wmax = max(wmax, __shfl_xor(wmax, 16));
  wmax = max(wmax, __shfl_xor(wmax, 32));

  size_t hoffA = (size_t)(dir*NB + bA)*NH;  // u32 index of this lane's load row
  const float* Gd = Gbase + (size_t)dir*NB*T*NG;
  // load bases (per parity): 64 dwordx2 loads all within offset 0..1944 of this base
  const unsigned long long* hb0 = (const unsigned long long*)&d_hx[grp][0][0] + ((hoffA + (size_t)koff)>>1);
  const unsigned long long* hb1 = (const unsigned long long*)&d_hx[grp][1][0] + ((hoffA + (size_t)koff)>>1);
  // store bases (per parity): q-th batch at +q*NH
  unsigned int* sb0 = &d_hx[grp][0][(size_t)(dir*NB + wv*16 + bq*4)*NH + u];
  unsigned int* sb1 = &d_hx[grp][1][(size_t)(dir*NB + wv*16 + bq*4)*NH + u];

  int ep = 1;
  lbar(dom, b5, agg, ep); ep++;                      // zeros + whs staged

  for(int t=0;t<T;t++){
    if(t < wmax){
      // --- G preactivations (normal cached loads, issued early) ---
      float gv[4][4];
      #pragma unroll
      for(int q=0;q<4;q++){
        int b = wv*16 + bq*4 + q;
        int pv = (dir==0)? t : (len4[q]-1-t);
        pv = (t<len4[q])? pv : 0;
        const float* gp = Gd + ((size_t)b*T+pv)*NG + u;
        gv[q][0]=gp[0]; gv[q][1]=gp[NH]; gv[q][2]=gp[2*NH]; gv[q][3]=gp[3*NH];
      }
      // --- h loads: 64 coherent dwordx2 from one base ---
      const unsigned long long* hb = (t&1)? hb1 : hb0;
      unsigned long long hx[64];
      #pragma unroll
      for(int kc=0;kc<16;kc++){
        #pragma unroll
        for(int j=0;j<4;j++){
          asm volatile("global_load_dwordx2 %0, %1, off offset:%2 sc1"
                       : "=v"(hx[kc*4+j]) : "v"(hb), "n"(kc*128 + j*8));
        }
      }
      asm volatile("s_waitcnt vmcnt(0)" ::: "memory");
      __builtin_amdgcn_sched_barrier(0);
      // --- recurrent MFMA ---
      f32x4 a0=0, a1=0, a2=0, a3=0;
      #pragma unroll
      for(int kc=0;kc<16;kc++){
        int kk = kc*32 + koff;
        unsigned long long x0=hx[kc*4+0],x1=hx[kc*4+1],x2=hx[kc*4+2],x3=hx[kc*4+3];
        unsigned int v0=(unsigned int)x0, v1=(unsigned int)(x0>>32),
                     v2=(unsigned int)x1, v3=(unsigned int)(x1>>32),
                     v4=(unsigned int)x2, v5=(unsigned int)(x2>>32),
                     v6=(unsigned int)x3, v7=(unsigned int)(x3>>32);
        U8 Hh, Hl;
        Hh.d[0]=(v1&0xFFFF0000u)|(v0>>16);  Hl.d[0]=(v1<<16)|(v0&0xFFFFu);
        Hh.d[1]=(v3&0xFFFF0000u)|(v2>>16);  Hl.d[1]=(v3<<16)|(v2&0xFFFFu);
        Hh.d[2]=(v5&0xFFFF0000u)|(v4>>16);  Hl.d[2]=(v5<<16)|(v4&0xFFFFu);
        Hh.d[3]=(v7&0xFFFF0000u)|(v6>>16);  Hl.d[3]=(v7<<16)|(v6&0xFFFFu);
        short8 w0 = *(const short8*)&whs[wb0 + (kk ^ swz)];
        short8 w1 = *(const short8*)&whs[wb1 + (kk ^ swz)];
        short8 w2 = *(const short8*)&whs[wb2 + (kk ^ swz)];
        short8 w3 = *(const short8*)&whs[wb3 + (kk ^ swz)];
        a0 = MFMA16(Hh.s, w0, a0); a0 = MFMA16(Hl.s, w0, a0);
        a1 = MFMA16(Hh.s, w1, a1); a1 = MFMA16(Hl.s, w1, a1);
        a2 = MFMA16(Hh.s, w2, a2); a2 = MFMA16(Hl.s, w2, a2);
        a3 = MFMA16(Hh.s, w3, a3); a3 = MFMA16(Hl.s, w3, a3);
      }
      // --- gates + state update + publish ---
      unsigned int* hsb_w = (t&1)? sb0 : sb1;        // parity (t+1)&1
      #pragma unroll
      for(int q=0;q<4;q++){
        int b = wv*16 + bq*4 + q;
        if(t < len4[q]){
          int pos = (dir==0) ? t : (len4[q]-1-t);
          float vi = a0[q] + gv[q][0];
          float vf = a1[q] + gv[q][1];
          float vg = a2[q] + gv[q][2];
          float vo = a3[q] + gv[q][3];
          float ig = 1.f/(1.f+__expf(-vi));
          float fg = 1.f/(1.f+__expf(-vf));
          float gg = tanhf(vg);
          float og = 1.f/(1.f+__expf(-vo));
          c4[q] = fg*c4[q] + ig*gg;
          h4[q] = og*tanhf(c4[q]);
          outb[((size_t)b*T+pos)*NH2 + dir*NH + u] = h4[q];
        }
        if(t <= len4[q]){                            // both parities current once frozen
          u16 hi, lo; split2(h4[q], hi, lo);
          unsigned int pk = ((unsigned int)hi<<16) | (unsigned int)lo;
          unsigned int* sp = hsb_w + (size_t)q*NH;
          asm volatile("global_store_dword %0, %1, off sc1" :: "v"(sp), "v"(pk) : "memory");
        }
      }
    }
    lbar(dom, b5, agg, ep); ep++;
  }
}

// ---------------- location weight + ctx pool + bf16 hi/lo side copies ----------------
__global__ void k_locpool(const float* __restrict__ w_u){
  int b = blockIdx.x; int d = blockIdx.y*128 + threadIdx.x;
  int alen = d_len[NB+b], sl = d_len[2*NB+b];
  int e_i = sl + alen - 1;
  float s = (float)sl, e = (float)e_i, sent = (float)TLC - (float)alen;
  float w3 = w_u[2*NH2 + d];
  float acc = 0.f;
  for(int t=0;t<TLC;t++){
    float w = (t < sl) ? (1.f - (s-(float)t)/sent) : ((t <= e_i) ? 0.f : (1.f - ((float)t-e)/sent));
    size_t ix = ((size_t)b*TLC + t)*NH2 + d;
    float v = d_ctx_out[ix] * w;
    d_ctx_out[ix] = v;
    u16 h,l; split2(v*w3, h, l);
    d_cw3h[ix]=h; d_cw3l[ix]=l;
    acc += v;
  }
  d_ctx_pool[b*NH2+d] = acc / (float)d_len[b];
}

__global__ void k_asppool(){
  int b = blockIdx.x; int d = blockIdx.y*128 + threadIdx.x;
  float acc=0.f;
  for(int t=0;t<TLA;t++){
    size_t ix = ((size_t)b*TLA+t)*NH2 + d; float v = d_asp_out[ix];
    u16 h,l; split2(v,h,l); d_abfh[ix]=h; d_abfl[ix]=l;
    acc += v;
  }
  d_asp_pool[b*NH2+d] = acc/(float)d_len[NB+b];
}

// ---------------- t = W(2H,2H) @ pool (associativity trick) ----------------
__global__ void k_tvec(const float* __restrict__ W, int sel){
  __shared__ float ps[NH2];
  int b = blockIdx.x; int k = blockIdx.y*64 + threadIdx.x;
  const float* pool = sel ? d_ctx_pool : d_asp_pool;
  float* out = sel ? d_tvec[1] : d_tvec[0];
  for(int i=threadIdx.x;i<NH2;i+=64) ps[i] = pool[b*NH2+i];
  __syncthreads();
  const float* wr = W + (size_t)k*NH2;
  float acc=0.f;
  for(int d=0;d<NH2;d+=4){
    float4 v = *(const float4*)(wr+d);
    acc += v.x*ps[d] + v.y*ps[d+1] + v.z*ps[d+2] + v.w*ps[d+3];
  }
  out[b*NH2+k] = acc;
}

// ---------------- av1 = ctx_out @ w1, av2 = asp_out @ w2 ----------------
__global__ void k_av(const float* __restrict__ w_u){
  int b = blockIdx.x; int wv = threadIdx.x>>6; int lane = threadIdx.x&63;
  int row = blockIdx.y*4 + wv;
  const float* src; const float* w; float* dst;
  if(row < TLC){ src = d_ctx_out + ((size_t)b*TLC+row)*NH2; w = w_u; dst = &d_av1[b*TLC+row]; }
  else { int j = row-TLC; src = d_asp_out + ((size_t)b*TLA+j)*NH2; w = w_u + NH2; dst = &d_av2[b*TLA+j]; }
  float acc=0.f;
  for(int d=lane*4; d<NH2; d+=256){
    float4 v = *(const float4*)(src+d);
    float4 ww = *(const float4*)(w+d);
    acc += v.x*ww.x + v.y*ww.y + v.z*ww.z + v.w*ww.w;
  }
  for(int o=32;o;o>>=1) acc += __shfl_down(acc,o);
  if(lane==0) *dst = acc;
}

// ---------------- align = av1 + av2 + (ctx*w3) @ asp^T (3-product hi/lo MFMA) ----------------
__global__ __launch_bounds__(256) void k_align(){
  int b = blockIdx.x; int tid = threadIdx.x; int wv = tid>>6, lane = tid&63;
  int i0 = wv*64; int r16 = lane&15; int koff = (lane>>4)*8;
  f32x4 acc[4][2] = {};
  const u16* Ahp = d_cw3h + (size_t)b*TLC*NH2;
  const u16* Alp = d_cw3l + (size_t)b*TLC*NH2;
  const u16* Bhp = d_abfh + (size_t)b*TLA*NH2;
  const u16* Blp = d_abfl + (size_t)b*TLA*NH2;
  for(int kc=0;kc<32;kc++){
    int k = kc*32 + koff;
    short8 fbh0 = *(const short8*)&Bhp[(size_t)r16*NH2 + k];
    short8 fbh1 = *(const short8*)&Bhp[(size_t)(16+r16)*NH2 + k];
    short8 fbl0 = *(const short8*)&Blp[(size_t)r16*NH2 + k];
    short8 fbl1 = *(const short8*)&Blp[(size_t)(16+r16)*NH2 + k];
    #pragma unroll
    for(int mi=0;mi<4;mi++){
      short8 fah = *(const short8*)&Ahp[(size_t)(i0+mi*16+r16)*NH2 + k];
      short8 fal = *(const short8*)&Alp[(size_t)(i0+mi*16+r16)*NH2 + k];
      acc[mi][0]=MFMA16(fah,fbh0,acc[mi][0]); acc[mi][0]=MFMA16(fal,fbh0,acc[mi][0]); acc[mi][0]=MFMA16(fah,fbl0,acc[mi][0]);
      acc[mi][1]=MFMA16(fah,fbh1,acc[mi][1]); acc[mi][1]=MFMA16(fal,fbh1,acc[mi][1]); acc[mi][1]=MFMA16(fah,fbl1,acc[mi][1]);
    }
  }
  int r4 = lane>>4;
  #pragma unroll
  for(int mi=0;mi<4;mi++)
  #pragma unroll
  for(int ni=0;ni<2;ni++){
    int jj = ni*16 + r16;
    float a2 = d_av2[b*TLA + jj];
    #pragma unroll
    for(int q=0;q<4;q++){
      int i = i0 + mi*16 + r4*4 + q;
      d_algn[((size_t)b*TLC + i)*TLA + jj] = acc[mi][ni][q] + d_av1[b*TLC+i] + a2;
    }
  }
}

// ---------------- attention features ----------------
__global__ __launch_bounds__(256) void k_attn(){
  __shared__ float sp[TLC];
  __shared__ float sq[TLA];
  __shared__ float st[NH2];
  __shared__ float red[256];
  int b = blockIdx.x; int tid = threadIdx.x;
  const float* cout = d_ctx_out + (size_t)b*TLC*NH2;
  const float* aout = d_asp_out + (size_t)b*TLA*NH2;

  { // P1: max over j, softmax over i
    const float* ar = d_algn + ((size_t)b*TLC + tid)*TLA;
    float m = ar[0];
    for(int j=1;j<TLA;j++) m = fmaxf(m, ar[j]);
    red[tid] = m; __syncthreads();
    for(int s=128;s;s>>=1){ if(tid<s) red[tid] = fmaxf(red[tid], red[tid+s]); __syncthreads(); }
    float M = red[0]; __syncthreads();
    float e_ = __expf(m - M);
    red[tid] = e_; __syncthreads();
    for(int s=128;s;s>>=1){ if(tid<s) red[tid] += red[tid+s]; __syncthreads(); }
    float S = red[0]; __syncthreads();
    sp[tid] = e_/S; __syncthreads();
  }
  // P2: f_asp2ctx
  for(int d=tid; d<NH2; d+=256){
    float a=0.f;
    for(int i=0;i<TLC;i++) a += sp[i]*cout[(size_t)i*NH2 + d];
    d_feat[1][b*NH2+d] = a;
  }
  __syncthreads();
  { // P3: c_asp2ctx via t_a2c
    for(int i2=tid;i2<NH2;i2+=256) st[i2] = d_tvec[0][b*NH2+i2];
    __syncthreads();
    const float* crow = cout + (size_t)tid*NH2;
    float lg = 0.f;
    for(int d=0;d<NH2;d+=4){ float4 v = *(const float4*)(crow+d); lg += v.x*st[d]+v.y*st[d+1]+v.z*st[d+2]+v.w*st[d+3]; }
    red[tid] = lg; __syncthreads();
    for(int s=128;s;s>>=1){ if(tid<s) red[tid] = fmaxf(red[tid], red[tid+s]); __syncthreads(); }
    float M = red[0]; __syncthreads();
    float e_ = __expf(lg - M);
    red[tid] = e_; __syncthreads();
    for(int s=128;s;s>>=1){ if(tid<s) red[tid] += red[tid+s]; __syncthreads(); }
    float S = red[0]; __syncthreads();
    sp[tid] = e_/S; __syncthreads();
    for(int d=tid; d<NH2; d+=256){
      float a=0.f;
      for(int i=0;i<TLC;i++) a += sp[i]*cout[(size_t)i*NH2 + d];
      d_feat[0][b*NH2+d] = a;
    }
    __syncthreads();
  }
  { // P4: max over i, softmax over j
    int jj = tid&31, grp = tid>>5;
    float pm = -1e30f;
    for(int i=grp;i<TLC;i+=8) pm = fmaxf(pm, d_algn[((size_t)b*TLC+i)*TLA + jj]);
    red[tid] = pm; __syncthreads();
    if(tid<32){
      float m2 = red[tid];
      for(int g=1;g<8;g++) m2 = fmaxf(m2, red[g*32+tid]);
      float Mx = m2;
      for(int o=16;o;o>>=1) Mx = fmaxf(Mx, __shfl_xor(Mx,o,32));
      float ee = __expf(m2 - Mx);
      float Ss = ee;
      for(int o=16;o;o>>=1) Ss += __shfl_xor(Ss,o,32);
      sq[tid] = ee/Ss;
    }
    __syncthreads();
  }
  // P5: f_ctx2asp
  for(int d=tid; d<NH2; d+=256){
    float a=0.f;
    for(int j=0;j<TLA;j++) a += sq[j]*aout[(size_t)j*NH2 + d];
    d_feat[2][b*NH2+d] = a;
  }
  __syncthreads();
  { // P6: c_ctx2asp logits via t_c2a
    for(int i2=tid;i2<NH2;i2+=256) st[i2] = d_tvec[1][b*NH2+i2];
    __syncthreads();
    int j6 = tid>>3, seg = tid&7;
    const float* arow = aout + (size_t)j6*NH2;
    float p6 = 0.f;
    for(int d=seg*128; d<seg*128+128; d+=4){ float4 v = *(const float4*)(arow+d); p6 += v.x*st[d]+v.y*st[d+1]+v.z*st[d+2]+v.w*st[d+3]; }
    red[tid] = p6; __syncthreads();
    if(tid<32){
      float lj = 0.f;
      for(int s=0;s<8;s++) lj += red[tid*8+s];
      float Mx = lj;
      for(int o=16;o;o>>=1) Mx = fmaxf(Mx, __shfl_xor(Mx,o,32));
      float ee = __expf(lj - Mx);
      float Ss = ee;
      for(int o=16;o;o>>=1) Ss += __shfl_xor(Ss,o,32);
      sq[tid] = ee/Ss;
    }
    __syncthreads();
  }
  // P7: c_ctx2asp
  for(int d=tid; d<NH2; d+=256){
    float a=0.f;
    for(int j=0;j<TLA;j++) a += sq[j]*aout[(size_t)j*NH2 + d];
    d_feat[3][b*NH2+d] = a;
  }
}

// ---------------- final dense ----------------
__global__ void k_final(const float* __restrict__ dw, const float* __restrict__ db, float* __restrict__ out){
  int b = blockIdx.x; int wv = threadIdx.x>>6; int lane = threadIdx.x&63;
  const float* fs[4] = {d_feat[0]+b*NH2, d_feat[1]+b*NH2, d_feat[2]+b*NH2, d_feat[3]+b*NH2};
  float acc=0.f;
  for(int e=lane*4; e<4096; e+=256){
    const float* f = fs[e>>10]; int d = e&1023;
    const float* w = dw + (size_t)wv*4096 + e;
    acc += f[d]*w[0] + f[d+1]*w[1] + f[d+2]*w[2] + f[d+3]*w[3];
  }
  for(int o=32;o;o>>=1) acc += __shfl_down(acc,o);
  if(lane==0) out[b*3+wv] = acc + db[wv];
}

// ---------------- host ----------------
extern "C" void kernel_launch(void* const* d_in, const int* in_sizes, int n_in,
                              void* d_out, int out_size, void* d_ws, size_t ws_size,
                              hipStream_t stream){
  const int*   traw  = (const int*)d_in[0];
  const int*   aidx  = (const int*)d_in[1];
  const int*   tleft = (const int*)d_in[2];
  const float* emb   = (const float*)d_in[3];
  const float* w_a2c = (const float*)d_in[4];
  const float* w_c2a = (const float*)d_in[5];
  const float* w_u   = (const float*)d_in[6];
  const float* dw    = (const float*)d_in[7];
  const float* db    = (const float*)d_in[8];
  // LSTM params: runs r=0..3 at d_in[9+4r..12+4r] = wih, whh, bih, bhh
  k_len<<<dim3(NB), dim3(64), 0, stream>>>(traw, aidx, tleft);
  k_prep_x<<<dim3(NB*TLC + NB*TLA), dim3(NEP), 0, stream>>>(traw, aidx, emb);
  k_prep_w<<<dim3(4*NG), dim3(NEP), 0, stream>>>(
      (const float*)d_in[9], (const float*)d_in[13], (const float*)d_in[17], (const float*)d_in[21],
      (const float*)d_in[11], (const float*)d_in[12], (const float*)d_in[15], (const float*)d_in[16],
      (const float*)d_in[19], (const float*)d_in[20], (const float*)d_in[23], (const float*)d_in[24]);
  k_zero<<<dim3(2048), dim3(256), 0, stream>>>();
  k_gin<<<dim3(32, 576), dim3(256), 0, stream>>>();
  k_lstm_all<<<dim3(128), dim3(256), 0, stream>>>(
      (const float*)d_in[10], (const float*)d_in[14], (const float*)d_in[18], (const float*)d_in[22]);
  k_locpool<<<dim3(NB, 8), dim3(128), 0, stream>>>(w_u);
  k_asppool<<<dim3(NB, 8), dim3(128), 0, stream>>>();
  k_tvec<<<dim3(NB, 16), dim3(64), 0, stream>>>(w_a2c, 0);
  k_tvec<<<dim3(NB, 16), dim3(64), 0, stream>>>(w_c2a, 1);
  k_av<<<dim3(NB, 72), dim3(256), 0, stream>>>(w_u);
  k_align<<<dim3(NB), dim3(256), 0, stream>>>();
  k_attn<<<dim3(NB), dim3(256), 0, stream>>>();
  k_final<<<dim3(NB), dim3(192), 0, stream>>>(dw, db, (float*)d_out);
}